// Round 2
// baseline (564.194 us; speedup 1.0000x reference)
//
#include <hip/hip_runtime.h>
#include <hip/hip_bf16.h>
#include <cstdint>
#include <cstddef>

#define HDIM 4096
#define MROWS 8192
#define LN_EPS 1e-5f

typedef __bf16 bf16_t;
typedef __bf16 bf16x4_t __attribute__((ext_vector_type(4)));
typedef __bf16 bf16x8_t __attribute__((ext_vector_type(8)));
typedef float f32x4_t __attribute__((ext_vector_type(4)));

typedef const __attribute__((address_space(1))) void gvoid_t;
typedef __attribute__((address_space(3))) void lvoid_t;

__device__ __forceinline__ float softplus_f(float x) {
    // logaddexp(x, 0) = max(x,0) + log1p(exp(-|x|)) (matches jax.nn.softplus)
    return fmaxf(x, 0.f) + log1pf(expf(-fabsf(x)));
}

// ---- W = mu + softplus(rho)*eps  -> bf16 ----
__global__ __launch_bounds__(256) void wgen_kernel(
    const float* __restrict__ mu, const float* __restrict__ rho,
    const float* __restrict__ eps, bf16_t* __restrict__ W)
{
    int i = (blockIdx.x * 256 + threadIdx.x) * 4;
    float4 m = *(const float4*)(mu + i);
    float4 r = *(const float4*)(rho + i);
    float4 e = *(const float4*)(eps + i);
    bf16x4_t o;
    o[0] = (bf16_t)(m.x + softplus_f(r.x) * e.x);
    o[1] = (bf16_t)(m.y + softplus_f(r.y) * e.y);
    o[2] = (bf16_t)(m.z + softplus_f(r.z) * e.z);
    o[3] = (bf16_t)(m.w + softplus_f(r.w) * e.w);
    *(bf16x4_t*)(W + i) = o;
}

// ---- bias = b_mu + softplus(b_rho)*eps_b  (fp32) ----
__global__ __launch_bounds__(256) void biasgen_kernel(
    const float* __restrict__ mu, const float* __restrict__ rho,
    const float* __restrict__ eps, float* __restrict__ b)
{
    int i = blockIdx.x * 256 + threadIdx.x;
    b[i] = mu[i] + softplus_f(rho[i]) * eps[i];
}

// ---- LayerNorm per row of 4096, fp32 in -> bf16 out ----
__global__ __launch_bounds__(256) void ln_kernel(
    const float* __restrict__ x, const float* __restrict__ gamma,
    const float* __restrict__ beta, bf16_t* __restrict__ h)
{
    int row = blockIdx.x;
    const float* xr = x + (size_t)row * HDIM;
    int t = threadIdx.x;
    float4 v[4];
    float s = 0.f, s2 = 0.f;
#pragma unroll
    for (int j = 0; j < 4; ++j) {
        v[j] = *(const float4*)(xr + j * 1024 + t * 4);
        s  += v[j].x + v[j].y + v[j].z + v[j].w;
        s2 += v[j].x * v[j].x + v[j].y * v[j].y + v[j].z * v[j].z + v[j].w * v[j].w;
    }
#pragma unroll
    for (int off = 32; off > 0; off >>= 1) {
        s  += __shfl_down(s, off);
        s2 += __shfl_down(s2, off);
    }
    __shared__ float ps[4], ps2[4];
    if ((t & 63) == 0) { ps[t >> 6] = s; ps2[t >> 6] = s2; }
    __syncthreads();
    float tot  = ps[0] + ps[1] + ps[2] + ps[3];
    float tot2 = ps2[0] + ps2[1] + ps2[2] + ps2[3];
    float mean = tot * (1.f / HDIM);
    float var  = tot2 * (1.f / HDIM) - mean * mean;
    float rstd = rsqrtf(var + LN_EPS);
    bf16_t* hr = h + (size_t)row * HDIM;
#pragma unroll
    for (int j = 0; j < 4; ++j) {
        int c = j * 1024 + t * 4;
        float4 g  = *(const float4*)(gamma + c);
        float4 bb = *(const float4*)(beta + c);
        bf16x4_t o;
        o[0] = (bf16_t)((v[j].x - mean) * rstd * g.x + bb.x);
        o[1] = (bf16_t)((v[j].y - mean) * rstd * g.y + bb.y);
        o[2] = (bf16_t)((v[j].z - mean) * rstd * g.z + bb.z);
        o[3] = (bf16_t)((v[j].w - mean) * rstd * g.w + bb.w);
        *(bf16x4_t*)(hr + c) = o;
    }
}

__device__ __forceinline__ void gload_lds16(const bf16_t* g, bf16_t* l) {
    __builtin_amdgcn_global_load_lds((gvoid_t*)g, (lvoid_t*)l, 16, 0, 0);
}

// ---- GEMM: out[m][o] = x[m][o] + gelu( sum_k h[m][k]*W[o][k] + bias[o] ) ----
// m97 structure: 128x128 tile, BK=32, 4 waves (2x2), 16x16x32 bf16 MFMA,
// global_load_lds width=16, single-buffered 2-barrier K-loop.
__global__ __launch_bounds__(256) void gemm_kernel(
    const bf16_t* __restrict__ A,   // [8192][4096] h (bf16)
    const bf16_t* __restrict__ B,   // [4096][4096] W (bf16, row=o col=k)
    const float* __restrict__ bias, // [4096]
    const float* __restrict__ xres, // [8192][4096] residual fp32
    float* __restrict__ out)        // [8192][4096]
{
    __shared__ bf16_t As[128 * 32];
    __shared__ bf16_t Bs[128 * 32];
    int tid  = threadIdx.x;
    int wave = tid >> 6, lane = tid & 63;
    int rowBase = blockIdx.y * 128;
    int colBase = blockIdx.x * 128;
    int wm = wave >> 1, wn = wave & 1;

    const bf16_t* Ab = A + (size_t)rowBase * HDIM;
    const bf16_t* Bb = B + (size_t)colBase * HDIM;
    // staging: lane l of wave w loads 16B; linear LDS byte off = w*1024 + r*4096 + l*16
    int srow = (wave << 4) + (lane >> 2);   // row within tile (r=0); r=1 adds 64
    int scol = (lane & 3) << 3;             // element col within BK
    bf16_t* AsW = As + wave * 512;          // wave-uniform LDS dest base
    bf16_t* BsW = Bs + wave * 512;

    f32x4_t acc[4][4] = {};

    int fr = lane & 15;           // fragment row (A) / output col (B)
    int fo = (lane >> 4) << 3;    // k offset within BK=32

    for (int k0 = 0; k0 < HDIM; k0 += 32) {
        gload_lds16(Ab + (size_t)srow * HDIM + k0 + scol, AsW);
        gload_lds16(Ab + (size_t)(srow + 64) * HDIM + k0 + scol, AsW + 2048);
        gload_lds16(Bb + (size_t)srow * HDIM + k0 + scol, BsW);
        gload_lds16(Bb + (size_t)(srow + 64) * HDIM + k0 + scol, BsW + 2048);
        __syncthreads();   // drains vmcnt(0): LDS tiles ready
        bf16x8_t af[4], bfr[4];
#pragma unroll
        for (int m = 0; m < 4; ++m)
            af[m] = *(const bf16x8_t*)&As[(wm * 64 + m * 16 + fr) * 32 + fo];
#pragma unroll
        for (int n = 0; n < 4; ++n)
            bfr[n] = *(const bf16x8_t*)&Bs[(wn * 64 + n * 16 + fr) * 32 + fo];
#pragma unroll
        for (int m = 0; m < 4; ++m)
#pragma unroll
            for (int n = 0; n < 4; ++n)
                acc[m][n] = __builtin_amdgcn_mfma_f32_16x16x32_bf16(
                    af[m], bfr[n], acc[m][n], 0, 0, 0);
        __syncthreads();   // all waves done reading before next stage
    }

    // epilogue: bias + exact GELU + residual, fp32 out
    // C/D layout (m89-verified): col = lane&15, row = (lane>>4)*4 + reg
    int col0 = colBase + wn * 64 + fr;
    int row0 = rowBase + wm * 64 + ((lane >> 4) << 2);
#pragma unroll
    for (int n = 0; n < 4; ++n) {
        float bv = bias[col0 + n * 16];
#pragma unroll
        for (int m = 0; m < 4; ++m) {
#pragma unroll
            for (int j = 0; j < 4; ++j) {
                size_t idx = (size_t)(row0 + m * 16 + j) * HDIM + (col0 + n * 16);
                float v = acc[m][n][j] + bv;
                float g = 0.5f * v * (1.0f + erff(v * 0.70710678118654752f));
                out[idx] = xres[idx] + g;
            }
        }
    }
}

extern "C" void kernel_launch(void* const* d_in, const int* in_sizes, int n_in,
                              void* d_out, int out_size, void* d_ws, size_t ws_size,
                              hipStream_t stream) {
    const float* x        = (const float*)d_in[0];
    const float* ln_gamma = (const float*)d_in[1];
    const float* ln_beta  = (const float*)d_in[2];
    const float* w_mu     = (const float*)d_in[3];
    const float* w_rho    = (const float*)d_in[4];
    const float* b_mu     = (const float*)d_in[5];
    const float* b_rho    = (const float*)d_in[6];
    const float* eps_w    = (const float*)d_in[7];
    const float* eps_b    = (const float*)d_in[8];
    float* out = (float*)d_out;

    char* ws = (char*)d_ws;
    bf16_t* h_bf16 = (bf16_t*)ws;                              // 8192*4096*2  = 64 MiB
    bf16_t* W_bf16 = (bf16_t*)(ws + 67108864);                 // 4096*4096*2  = 32 MiB
    float*  bias   = (float*)(ws + 67108864 + 33554432);       // 4096*4       = 16 KiB

    // W cast: 16.7M elems / 4 per thread / 256 per block = 16384 blocks
    wgen_kernel<<<16384, 256, 0, stream>>>(w_mu, w_rho, eps_w, W_bf16);
    biasgen_kernel<<<16, 256, 0, stream>>>(b_mu, b_rho, eps_b, bias);
    ln_kernel<<<MROWS, 256, 0, stream>>>(x, ln_gamma, ln_beta, h_bf16);
    gemm_kernel<<<dim3(HDIM / 128, MROWS / 128), 256, 0, stream>>>(
        h_bf16, W_bf16, bias, x, out);
}

// Round 3
// 440.298 us; speedup vs baseline: 1.2814x; 1.2814x over previous
//
#include <hip/hip_runtime.h>
#include <hip/hip_bf16.h>
#include <cstdint>
#include <cstddef>

#define HDIM 4096
#define MROWS 8192
#define LN_EPS 1e-5f

typedef __bf16 bf16_t;
typedef __bf16 bf16x4_t __attribute__((ext_vector_type(4)));
typedef __bf16 bf16x8_t __attribute__((ext_vector_type(8)));
typedef float f32x4_t __attribute__((ext_vector_type(4)));

typedef const __attribute__((address_space(1))) void gvoid_t;
typedef __attribute__((address_space(3))) void lvoid_t;

__device__ __forceinline__ float softplus_f(float x) {
    return fmaxf(x, 0.f) + log1pf(expf(-fabsf(x)));
}

// ---- W = mu + softplus(rho)*eps  -> bf16 ----
__global__ __launch_bounds__(256) void wgen_kernel(
    const float* __restrict__ mu, const float* __restrict__ rho,
    const float* __restrict__ eps, bf16_t* __restrict__ W)
{
    int i = (blockIdx.x * 256 + threadIdx.x) * 4;
    float4 m = *(const float4*)(mu + i);
    float4 r = *(const float4*)(rho + i);
    float4 e = *(const float4*)(eps + i);
    bf16x4_t o;
    o[0] = (bf16_t)(m.x + softplus_f(r.x) * e.x);
    o[1] = (bf16_t)(m.y + softplus_f(r.y) * e.y);
    o[2] = (bf16_t)(m.z + softplus_f(r.z) * e.z);
    o[3] = (bf16_t)(m.w + softplus_f(r.w) * e.w);
    *(bf16x4_t*)(W + i) = o;
}

// ---- bias = b_mu + softplus(b_rho)*eps_b  (fp32) ----
__global__ __launch_bounds__(256) void biasgen_kernel(
    const float* __restrict__ mu, const float* __restrict__ rho,
    const float* __restrict__ eps, float* __restrict__ b)
{
    int i = blockIdx.x * 256 + threadIdx.x;
    b[i] = mu[i] + softplus_f(rho[i]) * eps[i];
}

// ---- LayerNorm per row of 4096, fp32 in -> bf16 out ----
__global__ __launch_bounds__(256) void ln_kernel(
    const float* __restrict__ x, const float* __restrict__ gamma,
    const float* __restrict__ beta, bf16_t* __restrict__ h)
{
    int row = blockIdx.x;
    const float* xr = x + (size_t)row * HDIM;
    int t = threadIdx.x;
    float4 v[4];
    float s = 0.f, s2 = 0.f;
#pragma unroll
    for (int j = 0; j < 4; ++j) {
        v[j] = *(const float4*)(xr + j * 1024 + t * 4);
        s  += v[j].x + v[j].y + v[j].z + v[j].w;
        s2 += v[j].x * v[j].x + v[j].y * v[j].y + v[j].z * v[j].z + v[j].w * v[j].w;
    }
#pragma unroll
    for (int off = 32; off > 0; off >>= 1) {
        s  += __shfl_down(s, off);
        s2 += __shfl_down(s2, off);
    }
    __shared__ float ps[4], ps2[4];
    if ((t & 63) == 0) { ps[t >> 6] = s; ps2[t >> 6] = s2; }
    __syncthreads();
    float tot  = ps[0] + ps[1] + ps[2] + ps[3];
    float tot2 = ps2[0] + ps2[1] + ps2[2] + ps2[3];
    float mean = tot * (1.f / HDIM);
    float var  = tot2 * (1.f / HDIM) - mean * mean;
    float rstd = rsqrtf(var + LN_EPS);
    bf16_t* hr = h + (size_t)row * HDIM;
#pragma unroll
    for (int j = 0; j < 4; ++j) {
        int c = j * 1024 + t * 4;
        float4 g  = *(const float4*)(gamma + c);
        float4 bb = *(const float4*)(beta + c);
        bf16x4_t o;
        o[0] = (bf16_t)((v[j].x - mean) * rstd * g.x + bb.x);
        o[1] = (bf16_t)((v[j].y - mean) * rstd * g.y + bb.y);
        o[2] = (bf16_t)((v[j].z - mean) * rstd * g.z + bb.z);
        o[3] = (bf16_t)((v[j].w - mean) * rstd * g.w + bb.w);
        *(bf16x4_t*)(hr + c) = o;
    }
}

__device__ __forceinline__ void gload_lds16(const bf16_t* g, const char* l) {
    __builtin_amdgcn_global_load_lds((gvoid_t*)g, (lvoid_t*)l, 16, 0, 0);
}

// st-style LDS swizzle: flip byte bits 4,5 with row bits 1,2 (byte bits 7,8).
// Involution (bits 7,8 untouched). Confined to 512B blocks, so any >=512B-
// aligned base offset is transparent.
__device__ __forceinline__ int swz(int x) { return x ^ ((x >> 3) & 0x30); }

// ---- GEMM: out[m][o] = x[m][o] + gelu( sum_k h[m][k]*W[o][k] + bias[o] ) ----
// 256x256 tile, BK=32, 8 waves (2Mx4N), 4-deep LDS ring (4 x 32KB = 128KB),
// counted vmcnt(8) (tiles t+2,t+3 stay in flight across the barrier),
// lgkmcnt(0) before barrier, T2 swizzle both-sides, T5 setprio, T1 XCD swizzle.
__global__ __launch_bounds__(512, 2) void gemm_kernel(
    const bf16_t* __restrict__ A,   // [8192][4096] h (bf16)
    const bf16_t* __restrict__ B,   // [4096][4096] W (bf16, row=o col=k)
    const float* __restrict__ bias, // [4096]
    const float* __restrict__ xres, // [8192][4096] residual fp32
    float* __restrict__ out)        // [8192][4096]
{
    __shared__ char lds[131072];    // ring: buf b at b*32768; A at +0 (16KB), B at +16KB

    const int tid  = threadIdx.x;
    const int lane = tid & 63, w = tid >> 6;
    const int g = lane >> 4, fr = lane & 15;
    const int wm = w >> 2, wn = w & 3;   // wave grid 2(M) x 4(N)

    // T1: bijective XCD swizzle (512 blocks, 512%8==0)
    int bid = blockIdx.x;
    int wg  = (bid & 7) * 64 + (bid >> 3);
    const int tileN = (wg & 15) * 256;
    const int tileM = (wg >> 4) * 256;

    // ---- staging: linear LDS dest D = r*8192 + w*1024 + lane*16 (per region);
    // LDS[D] must hold linear-image value at S = swz(D)  (reader reads swz(P)).
    const bf16_t* srcA[2];
    const bf16_t* srcB[2];
    int ldstA[2], ldstB[2];
#pragma unroll
    for (int r = 0; r < 2; ++r) {
        int D = r * 8192 + w * 1024 + lane * 16;
        int S = swz(D);
        int row = S >> 6, colel = (S & 63) >> 1;
        srcA[r] = A + (size_t)(tileM + row) * HDIM + colel;
        srcB[r] = B + (size_t)(tileN + row) * HDIM + colel;
        ldstA[r] = r * 8192 + w * 1024;           // wave-uniform dest base
        ldstB[r] = 16384 + r * 8192 + w * 1024;
    }

    // ---- fragment ds_read offsets (swizzled, relative to buffer base) ----
    int aoff[8], boff[4];
#pragma unroll
    for (int m = 0; m < 8; ++m)
        aoff[m] = swz(wm * 8192 + m * 1024 + fr * 64 + g * 16);
#pragma unroll
    for (int n = 0; n < 4; ++n)
        boff[n] = 16384 + swz(wn * 4096 + n * 1024 + fr * 64 + g * 16);

    f32x4_t acc[8][4] = {};
    const int NT = HDIM / 32;  // 128 K-tiles

#define STAGE(bb, kofs)                                          \
    do {                                                         \
        gload_lds16(srcA[0] + (kofs), &lds[(bb) + ldstA[0]]);    \
        gload_lds16(srcA[1] + (kofs), &lds[(bb) + ldstA[1]]);    \
        gload_lds16(srcB[0] + (kofs), &lds[(bb) + ldstB[0]]);    \
        gload_lds16(srcB[1] + (kofs), &lds[(bb) + ldstB[1]]);    \
    } while (0)

    // prologue: stage tiles 0,1,2; ensure tile 0 landed (12 in flight -> 8)
    STAGE(0, 0);
    STAGE(32768, 32);
    STAGE(65536, 64);
    asm volatile("s_waitcnt vmcnt(8)" ::: "memory");
    __builtin_amdgcn_s_barrier();
    __builtin_amdgcn_sched_barrier(0);

#pragma unroll 1
    for (int t = 0; t < NT; ++t) {
        // stage tile t+3 into buf[(t+3)&3] (== buf[(t-1)&3], reads done at barrier)
        int ts = (t + 3) & (NT - 1);          // dummy wrap at tail: staged, never read
        STAGE(((t + 3) & 3) * 32768, ts * 32);

        const char* buf = &lds[(t & 3) * 32768];
        bf16x8_t af[8], bv[4];
#pragma unroll
        for (int m = 0; m < 8; ++m)
            af[m] = *(const bf16x8_t*)(buf + aoff[m]);
#pragma unroll
        for (int n = 0; n < 4; ++n)
            bv[n] = *(const bf16x8_t*)(buf + boff[n]);

        __builtin_amdgcn_s_setprio(1);
#pragma unroll
        for (int m = 0; m < 8; ++m)
#pragma unroll
            for (int n = 0; n < 4; ++n)
                acc[m][n] = __builtin_amdgcn_mfma_f32_16x16x32_bf16(
                    af[m], bv[n], acc[m][n], 0, 0, 0);
        __builtin_amdgcn_s_setprio(0);

        // all our ds_reads of buf[t&3] complete before crossing the barrier
        asm volatile("s_waitcnt lgkmcnt(0)" ::: "memory");
        // drain tile t+1's loads; keep t+2,t+3 (8 loads) in flight — never 0
        asm volatile("s_waitcnt vmcnt(8)" ::: "memory");
        __builtin_amdgcn_s_barrier();
        __builtin_amdgcn_sched_barrier(0);
    }
#undef STAGE

    // epilogue: bias + exact GELU + residual, fp32 out
    // C/D layout: col = lane&15, row = (lane>>4)*4 + j
    const int col0 = tileN + wn * 64 + fr;
    const int row0 = tileM + wm * 128 + g * 4;
#pragma unroll
    for (int n = 0; n < 4; ++n) {
        float bvv = bias[col0 + n * 16];
#pragma unroll
        for (int m = 0; m < 8; ++m) {
#pragma unroll
            for (int j = 0; j < 4; ++j) {
                size_t idx = (size_t)(row0 + m * 16 + j) * HDIM + (col0 + n * 16);
                float v = acc[m][n][j] + bvv;
                float ge = 0.5f * v * (1.0f + erff(v * 0.70710678118654752f));
                out[idx] = xres[idx] + ge;
            }
        }
    }
}

extern "C" void kernel_launch(void* const* d_in, const int* in_sizes, int n_in,
                              void* d_out, int out_size, void* d_ws, size_t ws_size,
                              hipStream_t stream) {
    const float* x        = (const float*)d_in[0];
    const float* ln_gamma = (const float*)d_in[1];
    const float* ln_beta  = (const float*)d_in[2];
    const float* w_mu     = (const float*)d_in[3];
    const float* w_rho    = (const float*)d_in[4];
    const float* b_mu     = (const float*)d_in[5];
    const float* b_rho    = (const float*)d_in[6];
    const float* eps_w    = (const float*)d_in[7];
    const float* eps_b    = (const float*)d_in[8];
    float* out = (float*)d_out;

    char* ws = (char*)d_ws;
    bf16_t* h_bf16 = (bf16_t*)ws;                              // 64 MiB
    bf16_t* W_bf16 = (bf16_t*)(ws + 67108864);                 // 32 MiB
    float*  bias   = (float*)(ws + 67108864 + 33554432);       // 16 KiB

    wgen_kernel<<<16384, 256, 0, stream>>>(w_mu, w_rho, eps_w, W_bf16);
    biasgen_kernel<<<16, 256, 0, stream>>>(b_mu, b_rho, eps_b, bias);
    ln_kernel<<<MROWS, 256, 0, stream>>>(x, ln_gamma, ln_beta, h_bf16);
    gemm_kernel<<<512, 512, 0, stream>>>(h_bf16, W_bf16, bias, x, out);
}

// Round 4
// 430.321 us; speedup vs baseline: 1.3111x; 1.0232x over previous
//
#include <hip/hip_runtime.h>
#include <hip/hip_bf16.h>
#include <cstdint>
#include <cstddef>

#define HDIM 4096
#define MROWS 8192
#define LN_EPS 1e-5f

typedef __bf16 bf16_t;
typedef __bf16 bf16x4_t __attribute__((ext_vector_type(4)));
typedef __bf16 bf16x8_t __attribute__((ext_vector_type(8)));
typedef float f32x4_t __attribute__((ext_vector_type(4)));

typedef const __attribute__((address_space(1))) void gvoid_t;
typedef __attribute__((address_space(3))) void lvoid_t;

__device__ __forceinline__ float softplus_f(float x) {
    return fmaxf(x, 0.f) + log1pf(expf(-fabsf(x)));
}

// ---- W = mu + softplus(rho)*eps  -> bf16 ----
__global__ __launch_bounds__(256) void wgen_kernel(
    const float* __restrict__ mu, const float* __restrict__ rho,
    const float* __restrict__ eps, bf16_t* __restrict__ W)
{
    int i = (blockIdx.x * 256 + threadIdx.x) * 4;
    float4 m = *(const float4*)(mu + i);
    float4 r = *(const float4*)(rho + i);
    float4 e = *(const float4*)(eps + i);
    bf16x4_t o;
    o[0] = (bf16_t)(m.x + softplus_f(r.x) * e.x);
    o[1] = (bf16_t)(m.y + softplus_f(r.y) * e.y);
    o[2] = (bf16_t)(m.z + softplus_f(r.z) * e.z);
    o[3] = (bf16_t)(m.w + softplus_f(r.w) * e.w);
    *(bf16x4_t*)(W + i) = o;
}

// ---- bias = b_mu + softplus(b_rho)*eps_b  (fp32) ----
__global__ __launch_bounds__(256) void biasgen_kernel(
    const float* __restrict__ mu, const float* __restrict__ rho,
    const float* __restrict__ eps, float* __restrict__ b)
{
    int i = blockIdx.x * 256 + threadIdx.x;
    b[i] = mu[i] + softplus_f(rho[i]) * eps[i];
}

// ---- LayerNorm per row of 4096, fp32 in -> bf16 out ----
__global__ __launch_bounds__(256) void ln_kernel(
    const float* __restrict__ x, const float* __restrict__ gamma,
    const float* __restrict__ beta, bf16_t* __restrict__ h)
{
    int row = blockIdx.x;
    const float* xr = x + (size_t)row * HDIM;
    int t = threadIdx.x;
    float4 v[4];
    float s = 0.f, s2 = 0.f;
#pragma unroll
    for (int j = 0; j < 4; ++j) {
        v[j] = *(const float4*)(xr + j * 1024 + t * 4);
        s  += v[j].x + v[j].y + v[j].z + v[j].w;
        s2 += v[j].x * v[j].x + v[j].y * v[j].y + v[j].z * v[j].z + v[j].w * v[j].w;
    }
#pragma unroll
    for (int off = 32; off > 0; off >>= 1) {
        s  += __shfl_down(s, off);
        s2 += __shfl_down(s2, off);
    }
    __shared__ float ps[4], ps2[4];
    if ((t & 63) == 0) { ps[t >> 6] = s; ps2[t >> 6] = s2; }
    __syncthreads();
    float tot  = ps[0] + ps[1] + ps[2] + ps[3];
    float tot2 = ps2[0] + ps2[1] + ps2[2] + ps2[3];
    float mean = tot * (1.f / HDIM);
    float var  = tot2 * (1.f / HDIM) - mean * mean;
    float rstd = rsqrtf(var + LN_EPS);
    bf16_t* hr = h + (size_t)row * HDIM;
#pragma unroll
    for (int j = 0; j < 4; ++j) {
        int c = j * 1024 + t * 4;
        float4 g  = *(const float4*)(gamma + c);
        float4 bb = *(const float4*)(beta + c);
        bf16x4_t o;
        o[0] = (bf16_t)((v[j].x - mean) * rstd * g.x + bb.x);
        o[1] = (bf16_t)((v[j].y - mean) * rstd * g.y + bb.y);
        o[2] = (bf16_t)((v[j].z - mean) * rstd * g.z + bb.z);
        o[3] = (bf16_t)((v[j].w - mean) * rstd * g.w + bb.w);
        *(bf16x4_t*)(hr + c) = o;
    }
}

__device__ __forceinline__ void gload_lds16(const bf16_t* g, const char* l) {
    __builtin_amdgcn_global_load_lds((gvoid_t*)g, (lvoid_t*)l, 16, 0, 0);
}

// st-style LDS swizzle: flip byte bits 4,5 with row bits 1,2 (byte bits 7,8).
// Involution (bits 7,8 untouched), confined to 512B blocks.
__device__ __forceinline__ int swz(int x) { return x ^ ((x >> 3) & 0x30); }

// ---- GEMM: out[m][o] = x[m][o] + gelu( sum_k h[m][k]*W[o][k] + bias[o] ) ----
// 256x256 tile, BK=32, 8 waves (2Mx4N), 4-deep LDS ring (4 x 32KB = 128KB).
// T3: each K-step split into 2 phases of {ds_read subtile | stage 1 half-tile |
// barrier | setprio+16 MFMA}; T4: counted vmcnt(8) once per K-step (tiles
// t+2,t+3 stay in flight); T2 swizzle both-sides; T5 setprio; T1 XCD swizzle.
// Ledger (same as proven round-3, plus 2 tightening mid-barriers):
//   WAR: stages of tile t+3 -> buf[(t-1)&3]; its reads drained by lgkmcnt(0)
//        before iteration t-1's final barrier; stages issue after it.
//   RAW: vmcnt(8) at end of iter t drains iter t-2's 4 stages (tile t+1)
//        before iter t+1 reads it; 8 loads (t+2,t+3) stay in flight.
__global__ __launch_bounds__(512, 2) void gemm_kernel(
    const bf16_t* __restrict__ A,   // [8192][4096] h (bf16)
    const bf16_t* __restrict__ B,   // [4096][4096] W (bf16, row=o col=k)
    const float* __restrict__ bias, // [4096]
    const float* __restrict__ xres, // [8192][4096] residual fp32
    float* __restrict__ out)        // [8192][4096]
{
    __shared__ char lds[131072];    // ring: buf b at b*32768; A at +0 (16KB), B at +16KB

    const int tid  = threadIdx.x;
    const int lane = tid & 63, w = tid >> 6;
    const int g = lane >> 4, fr = lane & 15;
    const int wm = w >> 2, wn = w & 3;   // wave grid 2(M) x 4(N)

    // T1: bijective XCD swizzle (512 blocks, 512%8==0)
    int bid = blockIdx.x;
    int wg  = (bid & 7) * 64 + (bid >> 3);
    const int tileN = (wg & 15) * 256;
    const int tileM = (wg >> 4) * 256;

    // staging: linear LDS dest D = r*8192 + w*1024 + lane*16 per region;
    // LDS[D] holds linear-image value at S = swz(D) (readers read swz(P)).
    const bf16_t* srcA[2];
    const bf16_t* srcB[2];
    int ldstA[2], ldstB[2];
#pragma unroll
    for (int r = 0; r < 2; ++r) {
        int D = r * 8192 + w * 1024 + lane * 16;
        int S = swz(D);
        int row = S >> 6, colel = (S & 63) >> 1;
        srcA[r] = A + (size_t)(tileM + row) * HDIM + colel;
        srcB[r] = B + (size_t)(tileN + row) * HDIM + colel;
        ldstA[r] = r * 8192 + w * 1024;           // wave-uniform dest base
        ldstB[r] = 16384 + r * 8192 + w * 1024;
    }

    // fragment ds_read offsets (swizzled, relative to buffer base)
    int aoff[8], boff[4];
#pragma unroll
    for (int m = 0; m < 8; ++m)
        aoff[m] = swz(wm * 8192 + m * 1024 + fr * 64 + g * 16);
#pragma unroll
    for (int n = 0; n < 4; ++n)
        boff[n] = 16384 + swz(wn * 4096 + n * 1024 + fr * 64 + g * 16);

    f32x4_t acc[8][4] = {};
    const int NT = HDIM / 32;  // 128 K-tiles

#define STAGE_A(bb, kofs)                                        \
    do {                                                         \
        gload_lds16(srcA[0] + (kofs), &lds[(bb) + ldstA[0]]);    \
        gload_lds16(srcA[1] + (kofs), &lds[(bb) + ldstA[1]]);    \
    } while (0)
#define STAGE_B(bb, kofs)                                        \
    do {                                                         \
        gload_lds16(srcB[0] + (kofs), &lds[(bb) + ldstB[0]]);    \
        gload_lds16(srcB[1] + (kofs), &lds[(bb) + ldstB[1]]);    \
    } while (0)

    // prologue: stage tiles 0,1,2 (12 calls); drain tile 0 (keep 8 in flight)
    STAGE_A(0, 0);      STAGE_B(0, 0);
    STAGE_A(32768, 32); STAGE_B(32768, 32);
    STAGE_A(65536, 64); STAGE_B(65536, 64);
    asm volatile("s_waitcnt vmcnt(8)" ::: "memory");
    __builtin_amdgcn_s_barrier();
    __builtin_amdgcn_sched_barrier(0);

#pragma unroll 1
    for (int t = 0; t < NT; ++t) {
        const char* buf = &lds[(t & 3) * 32768];
        const int sb = ((t + 3) & 3) * 32768;     // stage dest: buf[(t-1)&3]
        const int sk = ((t + 3) & (NT - 1)) * 32; // tail wrap: staged, never read

        // ---- phase 0: reads for M-half 0 + B, stage A halves of t+3 ----
        bf16x8_t af0, af1, af2, af3, bv0, bv1, bv2, bv3;
        af0 = *(const bf16x8_t*)(buf + aoff[0]);
        af1 = *(const bf16x8_t*)(buf + aoff[1]);
        af2 = *(const bf16x8_t*)(buf + aoff[2]);
        af3 = *(const bf16x8_t*)(buf + aoff[3]);
        bv0 = *(const bf16x8_t*)(buf + boff[0]);
        bv1 = *(const bf16x8_t*)(buf + boff[1]);
        bv2 = *(const bf16x8_t*)(buf + boff[2]);
        bv3 = *(const bf16x8_t*)(buf + boff[3]);
        STAGE_A(sb, sk);
        __builtin_amdgcn_s_barrier();
        __builtin_amdgcn_sched_barrier(0);
        __builtin_amdgcn_s_setprio(1);
        acc[0][0] = __builtin_amdgcn_mfma_f32_16x16x32_bf16(af0, bv0, acc[0][0], 0, 0, 0);
        acc[0][1] = __builtin_amdgcn_mfma_f32_16x16x32_bf16(af0, bv1, acc[0][1], 0, 0, 0);
        acc[0][2] = __builtin_amdgcn_mfma_f32_16x16x32_bf16(af0, bv2, acc[0][2], 0, 0, 0);
        acc[0][3] = __builtin_amdgcn_mfma_f32_16x16x32_bf16(af0, bv3, acc[0][3], 0, 0, 0);
        acc[1][0] = __builtin_amdgcn_mfma_f32_16x16x32_bf16(af1, bv0, acc[1][0], 0, 0, 0);
        acc[1][1] = __builtin_amdgcn_mfma_f32_16x16x32_bf16(af1, bv1, acc[1][1], 0, 0, 0);
        acc[1][2] = __builtin_amdgcn_mfma_f32_16x16x32_bf16(af1, bv2, acc[1][2], 0, 0, 0);
        acc[1][3] = __builtin_amdgcn_mfma_f32_16x16x32_bf16(af1, bv3, acc[1][3], 0, 0, 0);
        acc[2][0] = __builtin_amdgcn_mfma_f32_16x16x32_bf16(af2, bv0, acc[2][0], 0, 0, 0);
        acc[2][1] = __builtin_amdgcn_mfma_f32_16x16x32_bf16(af2, bv1, acc[2][1], 0, 0, 0);
        acc[2][2] = __builtin_amdgcn_mfma_f32_16x16x32_bf16(af2, bv2, acc[2][2], 0, 0, 0);
        acc[2][3] = __builtin_amdgcn_mfma_f32_16x16x32_bf16(af2, bv3, acc[2][3], 0, 0, 0);
        acc[3][0] = __builtin_amdgcn_mfma_f32_16x16x32_bf16(af3, bv0, acc[3][0], 0, 0, 0);
        acc[3][1] = __builtin_amdgcn_mfma_f32_16x16x32_bf16(af3, bv1, acc[3][1], 0, 0, 0);
        acc[3][2] = __builtin_amdgcn_mfma_f32_16x16x32_bf16(af3, bv2, acc[3][2], 0, 0, 0);
        acc[3][3] = __builtin_amdgcn_mfma_f32_16x16x32_bf16(af3, bv3, acc[3][3], 0, 0, 0);
        __builtin_amdgcn_s_setprio(0);
        __builtin_amdgcn_sched_barrier(0);

        // ---- phase 1: reads for M-half 1, stage B halves of t+3 ----
        bf16x8_t af4, af5, af6, af7;
        af4 = *(const bf16x8_t*)(buf + aoff[4]);
        af5 = *(const bf16x8_t*)(buf + aoff[5]);
        af6 = *(const bf16x8_t*)(buf + aoff[6]);
        af7 = *(const bf16x8_t*)(buf + aoff[7]);
        STAGE_B(sb, sk);
        __builtin_amdgcn_s_barrier();
        __builtin_amdgcn_sched_barrier(0);
        __builtin_amdgcn_s_setprio(1);
        acc[4][0] = __builtin_amdgcn_mfma_f32_16x16x32_bf16(af4, bv0, acc[4][0], 0, 0, 0);
        acc[4][1] = __builtin_amdgcn_mfma_f32_16x16x32_bf16(af4, bv1, acc[4][1], 0, 0, 0);
        acc[4][2] = __builtin_amdgcn_mfma_f32_16x16x32_bf16(af4, bv2, acc[4][2], 0, 0, 0);
        acc[4][3] = __builtin_amdgcn_mfma_f32_16x16x32_bf16(af4, bv3, acc[4][3], 0, 0, 0);
        acc[5][0] = __builtin_amdgcn_mfma_f32_16x16x32_bf16(af5, bv0, acc[5][0], 0, 0, 0);
        acc[5][1] = __builtin_amdgcn_mfma_f32_16x16x32_bf16(af5, bv1, acc[5][1], 0, 0, 0);
        acc[5][2] = __builtin_amdgcn_mfma_f32_16x16x32_bf16(af5, bv2, acc[5][2], 0, 0, 0);
        acc[5][3] = __builtin_amdgcn_mfma_f32_16x16x32_bf16(af5, bv3, acc[5][3], 0, 0, 0);
        acc[6][0] = __builtin_amdgcn_mfma_f32_16x16x32_bf16(af6, bv0, acc[6][0], 0, 0, 0);
        acc[6][1] = __builtin_amdgcn_mfma_f32_16x16x32_bf16(af6, bv1, acc[6][1], 0, 0, 0);
        acc[6][2] = __builtin_amdgcn_mfma_f32_16x16x32_bf16(af6, bv2, acc[6][2], 0, 0, 0);
        acc[6][3] = __builtin_amdgcn_mfma_f32_16x16x32_bf16(af6, bv3, acc[6][3], 0, 0, 0);
        acc[7][0] = __builtin_amdgcn_mfma_f32_16x16x32_bf16(af7, bv0, acc[7][0], 0, 0, 0);
        acc[7][1] = __builtin_amdgcn_mfma_f32_16x16x32_bf16(af7, bv1, acc[7][1], 0, 0, 0);
        acc[7][2] = __builtin_amdgcn_mfma_f32_16x16x32_bf16(af7, bv2, acc[7][2], 0, 0, 0);
        acc[7][3] = __builtin_amdgcn_mfma_f32_16x16x32_bf16(af7, bv3, acc[7][3], 0, 0, 0);
        __builtin_amdgcn_s_setprio(0);

        // end-of-iteration drain: all our ds_reads of buf[t&3] complete,
        // tile t+1's stages landed; tiles t+2,t+3 (8 loads) stay in flight.
        asm volatile("s_waitcnt lgkmcnt(0)" ::: "memory");
        asm volatile("s_waitcnt vmcnt(8)" ::: "memory");
        __builtin_amdgcn_s_barrier();
        __builtin_amdgcn_sched_barrier(0);
    }
#undef STAGE_A
#undef STAGE_B

    // epilogue: bias + exact GELU + residual, fp32 out
    // C/D layout: col = lane&15, row = (lane>>4)*4 + j
    const int col0 = tileN + wn * 64 + fr;
    const int row0 = tileM + wm * 128 + g * 4;
#pragma unroll
    for (int n = 0; n < 4; ++n) {
        float bvv = bias[col0 + n * 16];
#pragma unroll
        for (int m = 0; m < 8; ++m) {
#pragma unroll
            for (int j = 0; j < 4; ++j) {
                size_t idx = (size_t)(row0 + m * 16 + j) * HDIM + (col0 + n * 16);
                float v = acc[m][n][j] + bvv;
                float ge = 0.5f * v * (1.0f + erff(v * 0.70710678118654752f));
                out[idx] = xres[idx] + ge;
            }
        }
    }
}

extern "C" void kernel_launch(void* const* d_in, const int* in_sizes, int n_in,
                              void* d_out, int out_size, void* d_ws, size_t ws_size,
                              hipStream_t stream) {
    const float* x        = (const float*)d_in[0];
    const float* ln_gamma = (const float*)d_in[1];
    const float* ln_beta  = (const float*)d_in[2];
    const float* w_mu     = (const float*)d_in[3];
    const float* w_rho    = (const float*)d_in[4];
    const float* b_mu     = (const float*)d_in[5];
    const float* b_rho    = (const float*)d_in[6];
    const float* eps_w    = (const float*)d_in[7];
    const float* eps_b    = (const float*)d_in[8];
    float* out = (float*)d_out;

    char* ws = (char*)d_ws;
    bf16_t* h_bf16 = (bf16_t*)ws;                              // 64 MiB
    bf16_t* W_bf16 = (bf16_t*)(ws + 67108864);                 // 32 MiB
    float*  bias   = (float*)(ws + 67108864 + 33554432);       // 16 KiB

    wgen_kernel<<<16384, 256, 0, stream>>>(w_mu, w_rho, eps_w, W_bf16);
    biasgen_kernel<<<16, 256, 0, stream>>>(b_mu, b_rho, eps_b, bias);
    ln_kernel<<<MROWS, 256, 0, stream>>>(x, ln_gamma, ln_beta, h_bf16);
    gemm_kernel<<<512, 512, 0, stream>>>(h_bf16, W_bf16, bias, x, out);
}

// Round 5
// 425.858 us; speedup vs baseline: 1.3248x; 1.0105x over previous
//
#include <hip/hip_runtime.h>
#include <hip/hip_bf16.h>
#include <cstdint>
#include <cstddef>

#define HDIM 4096
#define MROWS 8192
#define LN_EPS 1e-5f

typedef __bf16 bf16_t;
typedef __bf16 bf16x4_t __attribute__((ext_vector_type(4)));
typedef __bf16 bf16x8_t __attribute__((ext_vector_type(8)));
typedef float f32x4_t __attribute__((ext_vector_type(4)));

typedef const __attribute__((address_space(1))) void gvoid_t;
typedef __attribute__((address_space(3))) void lvoid_t;

__device__ __forceinline__ float softplus_f(float x) {
    return fmaxf(x, 0.f) + log1pf(expf(-fabsf(x)));
}

// ---- W = mu + softplus(rho)*eps  -> bf16 ----
__global__ __launch_bounds__(256) void wgen_kernel(
    const float* __restrict__ mu, const float* __restrict__ rho,
    const float* __restrict__ eps, bf16_t* __restrict__ W)
{
    int i = (blockIdx.x * 256 + threadIdx.x) * 4;
    float4 m = *(const float4*)(mu + i);
    float4 r = *(const float4*)(rho + i);
    float4 e = *(const float4*)(eps + i);
    bf16x4_t o;
    o[0] = (bf16_t)(m.x + softplus_f(r.x) * e.x);
    o[1] = (bf16_t)(m.y + softplus_f(r.y) * e.y);
    o[2] = (bf16_t)(m.z + softplus_f(r.z) * e.z);
    o[3] = (bf16_t)(m.w + softplus_f(r.w) * e.w);
    *(bf16x4_t*)(W + i) = o;
}

// ---- bias = b_mu + softplus(b_rho)*eps_b  (fp32) ----
__global__ __launch_bounds__(256) void biasgen_kernel(
    const float* __restrict__ mu, const float* __restrict__ rho,
    const float* __restrict__ eps, float* __restrict__ b)
{
    int i = blockIdx.x * 256 + threadIdx.x;
    b[i] = mu[i] + softplus_f(rho[i]) * eps[i];
}

// ---- LayerNorm per row of 4096, fp32 in -> bf16 out ----
__global__ __launch_bounds__(256) void ln_kernel(
    const float* __restrict__ x, const float* __restrict__ gamma,
    const float* __restrict__ beta, bf16_t* __restrict__ h)
{
    int row = blockIdx.x;
    const float* xr = x + (size_t)row * HDIM;
    int t = threadIdx.x;
    float4 v[4];
    float s = 0.f, s2 = 0.f;
#pragma unroll
    for (int j = 0; j < 4; ++j) {
        v[j] = *(const float4*)(xr + j * 1024 + t * 4);
        s  += v[j].x + v[j].y + v[j].z + v[j].w;
        s2 += v[j].x * v[j].x + v[j].y * v[j].y + v[j].z * v[j].z + v[j].w * v[j].w;
    }
#pragma unroll
    for (int off = 32; off > 0; off >>= 1) {
        s  += __shfl_down(s, off);
        s2 += __shfl_down(s2, off);
    }
    __shared__ float ps[4], ps2[4];
    if ((t & 63) == 0) { ps[t >> 6] = s; ps2[t >> 6] = s2; }
    __syncthreads();
    float tot  = ps[0] + ps[1] + ps[2] + ps[3];
    float tot2 = ps2[0] + ps2[1] + ps2[2] + ps2[3];
    float mean = tot * (1.f / HDIM);
    float var  = tot2 * (1.f / HDIM) - mean * mean;
    float rstd = rsqrtf(var + LN_EPS);
    bf16_t* hr = h + (size_t)row * HDIM;
#pragma unroll
    for (int j = 0; j < 4; ++j) {
        int c = j * 1024 + t * 4;
        float4 g  = *(const float4*)(gamma + c);
        float4 bb = *(const float4*)(beta + c);
        bf16x4_t o;
        o[0] = (bf16_t)((v[j].x - mean) * rstd * g.x + bb.x);
        o[1] = (bf16_t)((v[j].y - mean) * rstd * g.y + bb.y);
        o[2] = (bf16_t)((v[j].z - mean) * rstd * g.z + bb.z);
        o[3] = (bf16_t)((v[j].w - mean) * rstd * g.w + bb.w);
        *(bf16x4_t*)(hr + c) = o;
    }
}

__device__ __forceinline__ void gload_lds16(const bf16_t* g, const char* l) {
    __builtin_amdgcn_global_load_lds((gvoid_t*)g, (lvoid_t*)l, 16, 0, 0);
}

// st-style LDS swizzle: flip byte bits 4,5 with bits 7,8. Involution,
// confined to 512B blocks.
__device__ __forceinline__ int swz(int x) { return x ^ ((x >> 3) & 0x30); }

// ---- GEMM: out[m][o] = x[m][o] + gelu( sum_k h[m][k]*W[o][k] + bias[o] ) ----
// 256x256 tile, BK=32, 8 waves (2Mx4N), 4-deep LDS ring (4 x 32KB).
// One-phase-lookahead pipeline: phase p issues ds_reads for phase p+1's MFMA,
// so ds latency hides under the MFMA cluster; counted lgkm waits are
// compiler-inserted (no lgkmcnt(0) in the loop). vmcnt(6) once per K-tile
// (3 half-tiles in flight). 2 barriers/iter. T1 XCD swizzle, T2 both-sides
// swizzle, T5 setprio. bv double-buffered by t-parity (loop unrolled x2).
//
// Hazard ledger:
//  WAR(stage): X(t) stages into buf[(t-1)&3]; every read of that buffer has
//    an MFMA consumer BEFORE the X(t) entry barrier, so all waves' reads
//    completed (not just issued) before any stage lands.
//  RAW(tile ready): vmcnt(6) before Y(t)'s entry barrier drains each wave's
//    own stages of tile t+1 (6 = A(t+2),B(t+2),A(t+3) still in flight);
//    barrier => all waves' t+1 stages landed before Y(t) reads tile t+1.
__global__ __launch_bounds__(512, 2) void gemm_kernel(
    const bf16_t* __restrict__ A,   // [8192][4096] h (bf16)
    const bf16_t* __restrict__ B,   // [4096][4096] W (bf16, row=o col=k)
    const float* __restrict__ bias, // [4096]
    const float* __restrict__ xres, // [8192][4096] residual fp32
    float* __restrict__ out)        // [8192][4096]
{
    __shared__ char lds[131072];    // ring: buf b at b*32768; A at +0, B at +16KB

    const int tid  = threadIdx.x;
    const int lane = tid & 63, w = tid >> 6;
    const int g = lane >> 4, fr = lane & 15;
    const int wm = w >> 2, wn = w & 3;   // wave grid 2(M) x 4(N)

    // T1: bijective XCD swizzle (512 blocks, 512%8==0)
    int bid = blockIdx.x;
    int wg  = (bid & 7) * 64 + (bid >> 3);
    const int tileN = (wg & 15) * 256;
    const int tileM = (wg >> 4) * 256;

    // staging: linear LDS dest D = r*8192 + w*1024 + lane*16 per region;
    // LDS[D] holds linear-image value at S = swz(D).
    const bf16_t* srcA[2];
    const bf16_t* srcB[2];
    int ldstA[2], ldstB[2];
#pragma unroll
    for (int r = 0; r < 2; ++r) {
        int D = r * 8192 + w * 1024 + lane * 16;
        int S = swz(D);
        int row = S >> 6, colel = (S & 63) >> 1;
        srcA[r] = A + (size_t)(tileM + row) * HDIM + colel;
        srcB[r] = B + (size_t)(tileN + row) * HDIM + colel;
        ldstA[r] = r * 8192 + w * 1024;
        ldstB[r] = 16384 + r * 8192 + w * 1024;
    }

    // fragment ds_read offsets (swizzled, relative to buffer base)
    int aoff[8], boff[4];
#pragma unroll
    for (int m = 0; m < 8; ++m)
        aoff[m] = swz(wm * 8192 + m * 1024 + fr * 64 + g * 16);
#pragma unroll
    for (int n = 0; n < 4; ++n)
        boff[n] = 16384 + swz(wn * 4096 + n * 1024 + fr * 64 + g * 16);

    f32x4_t acc[8][4] = {};
    const int NT = HDIM / 32;  // 128 K-tiles

    bf16x8_t af0, af1, af2, af3, af4, af5, af6, af7;
    bf16x8_t bvA0, bvA1, bvA2, bvA3, bvB0, bvB1, bvB2, bvB3;

#define STAGE_A(bb, kofs)                                        \
    do {                                                         \
        gload_lds16(srcA[0] + (kofs), &lds[(bb) + ldstA[0]]);    \
        gload_lds16(srcA[1] + (kofs), &lds[(bb) + ldstA[1]]);    \
    } while (0)
#define STAGE_B(bb, kofs)                                        \
    do {                                                         \
        gload_lds16(srcB[0] + (kofs), &lds[(bb) + ldstB[0]]);    \
        gload_lds16(srcB[1] + (kofs), &lds[(bb) + ldstB[1]]);    \
    } while (0)
#define RD_SET1(bp)                                  \
    af4 = *(const bf16x8_t*)((bp) + aoff[4]);        \
    af5 = *(const bf16x8_t*)((bp) + aoff[5]);        \
    af6 = *(const bf16x8_t*)((bp) + aoff[6]);        \
    af7 = *(const bf16x8_t*)((bp) + aoff[7]);
#define RD_SET0(bp, V)                               \
    af0 = *(const bf16x8_t*)((bp) + aoff[0]);        \
    af1 = *(const bf16x8_t*)((bp) + aoff[1]);        \
    af2 = *(const bf16x8_t*)((bp) + aoff[2]);        \
    af3 = *(const bf16x8_t*)((bp) + aoff[3]);        \
    V##0 = *(const bf16x8_t*)((bp) + boff[0]);       \
    V##1 = *(const bf16x8_t*)((bp) + boff[1]);       \
    V##2 = *(const bf16x8_t*)((bp) + boff[2]);       \
    V##3 = *(const bf16x8_t*)((bp) + boff[3]);
#define CL(AF, V, R)                                                            \
    acc[R][0] = __builtin_amdgcn_mfma_f32_16x16x32_bf16(AF, V##0, acc[R][0], 0, 0, 0); \
    acc[R][1] = __builtin_amdgcn_mfma_f32_16x16x32_bf16(AF, V##1, acc[R][1], 0, 0, 0); \
    acc[R][2] = __builtin_amdgcn_mfma_f32_16x16x32_bf16(AF, V##2, acc[R][2], 0, 0, 0); \
    acc[R][3] = __builtin_amdgcn_mfma_f32_16x16x32_bf16(AF, V##3, acc[R][3], 0, 0, 0);
#define SCHEDB __builtin_amdgcn_sched_barrier(0)
#define BARRIER do { __builtin_amdgcn_s_barrier(); SCHEDB; } while (0)
#define VMCNT6 do { asm volatile("s_waitcnt vmcnt(6)" ::: "memory"); SCHEDB; } while (0)

    // Phase X(t): reads SET1(t) for this tile's 2nd cluster; stage A(t+3);
    //             MFMA af0-3(t) x bv(t)  (read in previous Y phase).
#define PHASE_X(tc, V)                                               \
    do {                                                             \
        BARRIER;                                                     \
        const char* bp_ = &lds[((tc) & 3) * 32768];                  \
        RD_SET1(bp_);                                                \
        STAGE_A((((tc) + 3) & 3) * 32768, (((tc) + 3) & (NT - 1)) * 32); \
        SCHEDB;                                                      \
        __builtin_amdgcn_s_setprio(1);                               \
        CL(af0, V, 0) CL(af1, V, 1) CL(af2, V, 2) CL(af3, V, 3)      \
        __builtin_amdgcn_s_setprio(0);                               \
        SCHEDB;                                                      \
        VMCNT6;                                                      \
    } while (0)
    // Phase Y(t): reads SET0(t+1) into the OTHER bv bank; stage B(t+3);
    //             MFMA af4-7(t) x bv(t).
#define PHASE_Y(tc, Vnext, Vcur)                                     \
    do {                                                             \
        BARRIER;                                                     \
        const char* bp_ = &lds[(((tc) + 1) & 3) * 32768];            \
        RD_SET0(bp_, Vnext);                                         \
        STAGE_B((((tc) + 3) & 3) * 32768, (((tc) + 3) & (NT - 1)) * 32); \
        SCHEDB;                                                      \
        __builtin_amdgcn_s_setprio(1);                               \
        CL(af4, Vcur, 4) CL(af5, Vcur, 5) CL(af6, Vcur, 6) CL(af7, Vcur, 7) \
        __builtin_amdgcn_s_setprio(0);                               \
        SCHEDB;                                                      \
    } while (0)

    // prologue: stage tiles 0,1,2; drain tile 0 (keep A1,B1,A2,B2 = 8)
    STAGE_A(0, 0);      STAGE_B(0, 0);
    STAGE_A(32768, 32); STAGE_B(32768, 32);
    STAGE_A(65536, 64); STAGE_B(65536, 64);
    asm volatile("s_waitcnt vmcnt(8)" ::: "memory");
    BARRIER;
    RD_SET0(&lds[0], bvA);   // SET0(0)

#pragma unroll 1
    for (int t = 0; t < NT; t += 2) {
        PHASE_X(t, bvA);
        PHASE_Y(t, bvB, bvA);
        PHASE_X(t + 1, bvB);
        PHASE_Y(t + 1, bvA, bvB);
    }
#undef PHASE_X
#undef PHASE_Y
#undef STAGE_A
#undef STAGE_B

    // epilogue: bias + exact GELU + residual, fp32 out
    // C/D layout: col = lane&15, row = (lane>>4)*4 + j
    const int col0 = tileN + wn * 64 + fr;
    const int row0 = tileM + wm * 128 + g * 4;
#pragma unroll
    for (int n = 0; n < 4; ++n) {
        float bvv = bias[col0 + n * 16];
#pragma unroll
        for (int m = 0; m < 8; ++m) {
#pragma unroll
            for (int j = 0; j < 4; ++j) {
                size_t idx = (size_t)(row0 + m * 16 + j) * HDIM + (col0 + n * 16);
                float v = acc[m][n][j] + bvv;
                float ge = 0.5f * v * (1.0f + erff(v * 0.70710678118654752f));
                out[idx] = xres[idx] + ge;
            }
        }
    }
}

extern "C" void kernel_launch(void* const* d_in, const int* in_sizes, int n_in,
                              void* d_out, int out_size, void* d_ws, size_t ws_size,
                              hipStream_t stream) {
    const float* x        = (const float*)d_in[0];
    const float* ln_gamma = (const float*)d_in[1];
    const float* ln_beta  = (const float*)d_in[2];
    const float* w_mu     = (const float*)d_in[3];
    const float* w_rho    = (const float*)d_in[4];
    const float* b_mu     = (const float*)d_in[5];
    const float* b_rho    = (const float*)d_in[6];
    const float* eps_w    = (const float*)d_in[7];
    const float* eps_b    = (const float*)d_in[8];
    float* out = (float*)d_out;

    char* ws = (char*)d_ws;
    bf16_t* h_bf16 = (bf16_t*)ws;                              // 64 MiB
    bf16_t* W_bf16 = (bf16_t*)(ws + 67108864);                 // 32 MiB
    float*  bias   = (float*)(ws + 67108864 + 33554432);       // 16 KiB

    wgen_kernel<<<16384, 256, 0, stream>>>(w_mu, w_rho, eps_w, W_bf16);
    biasgen_kernel<<<16, 256, 0, stream>>>(b_mu, b_rho, eps_b, bias);
    ln_kernel<<<MROWS, 256, 0, stream>>>(x, ln_gamma, ln_beta, h_bf16);
    gemm_kernel<<<512, 512, 0, stream>>>(h_bf16, W_bf16, bias, x, out);
}